// Round 11
// baseline (71.610 us; speedup 1.0000x reference)
//
#include <hip/hip_runtime.h>

#define NIN 64
#define NOUT 64
#define NTO 16
#define HH 192
#define WW 192
#define HO 190
#define WO 190
#define WBUF 5120            // per-wave buffer: 18 rows x 17 units(16B) = 4896 B + 224 pad
#define NBLK 2304            // 36 groups (9 tiles x 4 batch) x 64 out channels

typedef const __attribute__((address_space(1))) void gv_t;
typedef __attribute__((address_space(3))) void lv_t;

__global__ __launch_bounds__(256, 7) void scm_kernel(
    const float* __restrict__ x,
    const float* __restrict__ w,
    const float* __restrict__ bias,
    const int* __restrict__ conn_in,
    float* __restrict__ out)
{
    __shared__ char smem[4 * WBUF];   // 20480 B: 4 waves x single wave-private buffer

    const int tid  = threadIdx.x;
    const int lane = tid & 63;
    const int tx   = tid & 15;       // col group of 4
    const int ty   = tid >> 4;       // row group of 4 (block-wide)
    const int wv   = ty >> 2;        // wave id 0..3 (rows 16*wv .. +15)
    const int lty  = ty & 3;         // row group within wave

    // XCD-aware swizzle (bijective, 2304 % 8 == 0), o-minor for L2 gather reuse.
    const int lid = (blockIdx.x & 7) * (NBLK / 8) + (blockIdx.x >> 3);
    const int o   = lid & 63;
    const int g   = lid >> 6;        // 0..35
    const int tile = g % 9;
    const int b    = g / 9;
    const int i0 = (tile / 3) * 64;
    const int j0 = (tile % 3) * 64;

    // ---- Wave-private LDS layout (5120 B): 18 rows x 17 units of 16B
    // (272 B row stride, halo inline as unit 16). Bytes 4896..5119 = pad.
    // Staged by 5 global_load_lds rounds; physical unit u = s*64+lane.
    // Clamped slots feed only outputs >= row/col 190 (discarded).
    int goff[5];
    #pragma unroll
    for (int s = 0; s < 5; ++s) {
        int u = s * 64 + lane;
        int gr, gc;
        if (u < 306) {
            int row = u / 17;
            int uc  = u - row * 17;
            gr = i0 + 16 * wv + row;
            gc = j0 + 4 * uc; if (gc > 188) gc = 188;
        } else { gr = 191; gc = 0; }
        if (gr > 191) gr = 191;
        goff[s] = (gr * WW + gc) * 4;
    }

    char* wbase = smem + wv * WBUF;
    // Read base (channel-independent): row lr = lty*4+r at byte lr*272 + tx*16.
    // Both reads are contiguous b128 (no b64 anywhere in the read path).
    const char* rbase = wbase + lty * 1088 + tx * 16;

    const char* xb = (const char*)x + (size_t)b * NIN * HH * WW * 4;
    const int kbase = o * NTO;

    float acc[4][4];
    #pragma unroll
    for (int i = 0; i < 4; ++i)
        #pragma unroll
        for (int p = 0; p < 4; ++p) acc[i][p] = 0.f;

    #pragma unroll 1
    for (int t = 0; t < NTO; ++t) {
        // Previous-channel ds_reads must retire before overwriting the
        // wave-private buffer. Wave-local, essentially free.
        asm volatile("s_waitcnt lgkmcnt(0)" ::: "memory");
        __builtin_amdgcn_sched_barrier(0);

        const int ci = __builtin_amdgcn_readfirstlane(conn_in[kbase + t]);
        {
            const char* src = xb + (size_t)ci * (HH * WW * 4);
            #pragma unroll
            for (int s = 0; s < 5; ++s)
                __builtin_amdgcn_global_load_lds((gv_t*)(src + goff[s]),
                                                 (lv_t*)(wbase + s * 1024),
                                                 16, 0, 0);
        }

        // Scalar weight loads overlap the DMA wait.
        float wv9[9];
        #pragma unroll
        for (int q = 0; q < 9; ++q) wv9[q] = w[(kbase + t) * 9 + q];

        asm volatile("s_waitcnt vmcnt(0)" ::: "memory");
        __builtin_amdgcn_sched_barrier(0);

        #pragma unroll
        for (int r = 0; r < 6; ++r) {
            const float4 v4 = *(const float4*)(rbase + r * 272);
            const float4 vb = *(const float4*)(rbase + r * 272 + 16);
            const float rowv[6] = {v4.x, v4.y, v4.z, v4.w, vb.x, vb.y};
            #pragma unroll
            for (int i = 0; i < 4; ++i) {
                const int kh = r - i;
                if (kh >= 0 && kh < 3) {
                    #pragma unroll
                    for (int kw = 0; kw < 3; ++kw) {
                        const float wk = wv9[kh * 3 + kw];
                        #pragma unroll
                        for (int p = 0; p < 4; ++p)
                            acc[i][p] = fmaf(wk, rowv[p + kw], acc[i][p]);
                    }
                }
            }
        }
    }

    const float bv = bias[o];
    float* outp = out + (size_t)(b * NOUT + o) * (HO * WO);
    #pragma unroll
    for (int i = 0; i < 4; ++i) {
        const int gi = i0 + ty * 4 + i;
        if (gi < HO) {
            const int gj = j0 + tx * 4;
            float* row = outp + (size_t)gi * WO + gj;
            if (gj + 3 < WO) {
                *(float2*)(row)     = make_float2(acc[i][0] + bv, acc[i][1] + bv);
                *(float2*)(row + 2) = make_float2(acc[i][2] + bv, acc[i][3] + bv);
            } else {
                #pragma unroll
                for (int p = 0; p < 4; ++p)
                    if (gj + p < WO) row[p] = acc[i][p] + bv;
            }
        }
    }
}

extern "C" void kernel_launch(void* const* d_in, const int* in_sizes, int n_in,
                              void* d_out, int out_size, void* d_ws, size_t ws_size,
                              hipStream_t stream) {
    const float* x       = (const float*)d_in[0];
    const float* weight  = (const float*)d_in[1];
    const float* bias    = (const float*)d_in[2];
    const int*   conn_in = (const int*)d_in[3];
    // d_in[4] = conn_out (implicit: k -> k/16)

    dim3 grid(NBLK);
    dim3 block(256);
    scm_kernel<<<grid, block, 0, stream>>>(x, weight, bias, conn_in, (float*)d_out);
}